// Round 14
// baseline (351.799 us; speedup 1.0000x reference)
//
#include <hip/hip_runtime.h>
#include <hip/hip_bf16.h>
#include <math.h>

// BiMambaEncoderLayer: B=2, L=2048, D_MODEL=512, ED=1024, N=16, DCONV=4,
// DT_RANK=32, D_FF=1024. f32 in/out.
// Round-29: bgemm4 -> bgemm5 = the T4 counted-vmcnt pipeline the round-7
// attempt missed. Round-7's 2-phase dbuf used __syncthreads (vmcnt DRAIN
// to 0) -- m218 measured drain0 == no pipeline. bgemm5: BK=32 dbuf,
// STAGE(t+1) stays IN FLIGHT under COMPUTE(t) via inline-asm
// s_waitcnt vmcnt(NC) (NC = next-tile loads/thread: 3 for 128x64, 2 for
// 64x64) + RAW s_barrier (no drain); second plain barrier guards buffer
// reuse. Compiler fences (empty asm w/ memory clobber) around barriers.
// Applied to G1/G4/G5/G6 only; zgate3/g2m2/conv3/scan6/g3m/ln/prep
// byte-for-byte from round-28 (≈344.4us). 11 dispatches, 48.4 MiB ws.

#define BD 2
#define LD 2048
#define DMODEL 512
#define EDIM 1024
#define NST 16
#define DTR 32
#define DFF 1024
#define MROWS (BD*LD)   // 4096

typedef __hip_bfloat16 bf16;
typedef __bf16 bf16x8 __attribute__((ext_vector_type(8)));
typedef __bf16 bf16x4 __attribute__((ext_vector_type(4)));
typedef float  f32x4  __attribute__((ext_vector_type(4)));

__device__ __forceinline__ float sig_(float x) { return 1.f / (1.f + __expf(-x)); }

// async 16B global->LDS (wave-uniform LDS base, per-lane global addr)
__device__ __forceinline__ void glds16(const void* g, void* l)
{
    __builtin_amdgcn_global_load_lds(
        (const __attribute__((address_space(1))) void*)g,
        (__attribute__((address_space(3))) void*)l, 16, 0, 0);
}

// counted vmcnt wait (literal per template) — T4: never drain to 0 in-loop
template<int N> __device__ __forceinline__ void vmw_()
{
    if constexpr (N == 0)      asm volatile("s_waitcnt vmcnt(0)" ::: "memory");
    else if constexpr (N == 2) asm volatile("s_waitcnt vmcnt(2)" ::: "memory");
    else if constexpr (N == 3) asm volatile("s_waitcnt vmcnt(3)" ::: "memory");
    else if constexpr (N == 4) asm volatile("s_waitcnt vmcnt(4)" ::: "memory");
}
// raw barrier with compile-time memory fences (no vmcnt/lgkm drain)
__device__ __forceinline__ void bar_()
{
    asm volatile("" ::: "memory");
    __builtin_amdgcn_s_barrier();
    asm volatile("" ::: "memory");
}

// ---------------- prep: all weight transposes + x->bf16, one dispatch --------
// [0,2048) xconv | [2048,4096) inwT | [4096,5120) outwT | [5120,5632) fw1T |
// [5632,6144) fw2T | [6144,6272) xpT | [6272,6336) dtwT
__global__ __launch_bounds__(256)
void prep_k(const float* __restrict__ x, bf16* __restrict__ xbf,
            const float* __restrict__ inw_f, const float* __restrict__ inw_b,
            bf16* __restrict__ inwT,
            const float* __restrict__ outw_f, const float* __restrict__ outw_b,
            bf16* __restrict__ outwT,
            const float* __restrict__ fw1, bf16* __restrict__ fw1T,
            const float* __restrict__ fw2, bf16* __restrict__ fw2T,
            const float* __restrict__ xp_f, const float* __restrict__ xp_b,
            bf16* __restrict__ xpT,
            const float* __restrict__ dtw_f, const float* __restrict__ dtw_b,
            bf16* __restrict__ dtwT)
{
    const int bid = blockIdx.x, tid = threadIdx.x;
    if (bid < 2048) {
        size_t i = (size_t)bid * 1024 + tid * 4;
        float4 v = *(const float4*)(x + i);
        bf16* o = xbf + i;
        o[0] = __float2bfloat16(v.x); o[1] = __float2bfloat16(v.y);
        o[2] = __float2bfloat16(v.z); o[3] = __float2bfloat16(v.w);
        return;
    }
    const float* W; bf16* WT; int R, C, cx, ry;
    if (bid < 4096) {
        int d = (bid - 2048) >> 10, t = (bid - 2048) & 1023;
        W = d ? inw_b : inw_f; WT = inwT + (size_t)d * 2048 * 512;
        R = 512; C = 2048; cx = t & 63; ry = t >> 6;
    } else if (bid < 5120) {
        int d = (bid - 4096) >> 9, t = (bid - 4096) & 511;
        W = d ? outw_b : outw_f; WT = outwT + (size_t)d * 512 * 1024;
        R = 1024; C = 512; cx = t & 15; ry = t >> 4;
    } else if (bid < 5632) {
        int t = bid - 5120; W = fw1; WT = fw1T; R = 512; C = 1024;
        cx = t & 31; ry = t >> 5;
    } else if (bid < 6144) {
        int t = bid - 5632; W = fw2; WT = fw2T; R = 1024; C = 512;
        cx = t & 15; ry = t >> 4;
    } else if (bid < 6272) {
        int d = (bid - 6144) >> 6, t = (bid - 6144) & 63;
        W = d ? xp_b : xp_f; WT = xpT + (size_t)d * 64 * 1024;
        R = 1024; C = 64; cx = t & 1; ry = t >> 1;
    } else {
        int d = (bid - 6272) >> 5, t = (bid - 6272) & 31;
        W = d ? dtw_b : dtw_f; WT = dtwT + (size_t)d * 1024 * DTR;
        R = 32; C = 1024; cx = t; ry = 0;
    }
    __shared__ float tt[32][33];
    const int c0 = cx * 32, r0 = ry * 32;
    const int col = tid & 31, rr = tid >> 5;
#pragma unroll
    for (int p = 0; p < 4; ++p)
        tt[p * 8 + rr][col] = W[(size_t)(r0 + p * 8 + rr) * C + c0 + col];
    __syncthreads();
#pragma unroll
    for (int p = 0; p < 4; ++p)
        WT[(size_t)(c0 + p * 8 + rr) * R + r0 + col] =
            __float2bfloat16(tt[col][p * 8 + rr]);
}

// ---------------- bgemm5: BMxBN MFMA GEMM, BK=32 dbuf, counted vmcnt --------
// STAGE(t+1) stays in flight under COMPUTE(t): vmcnt(NC)+raw barrier
// (NC = loads/thread of ONE stage = BM/64+BN/64). Drain-0 only at epilogue.
template<int BM, int BN, int MODE, bool FLIPD1, bool CATK>
__global__ __launch_bounds__(256)
void bgemm5_k(const bf16* __restrict__ A, size_t Astr, int lda,
              const bf16* __restrict__ BT, size_t Bstr, int ldb,
              const float* __restrict__ bias,
              bf16* __restrict__ Cb, size_t Cstr, int ldc,
              const bf16* __restrict__ mp, size_t mpStr,
              float* __restrict__ outp, int K)
{
    constexpr int BK = 32;
    constexpr int FRm = BM / 32, FRn = BN / 32;
    constexpr int KH = DFF;              // concat-K half length (1024)
    constexpr int NC = BM / 64 + BN / 64; // glds16 calls per thread per stage
    __shared__ __align__(16) bf16 As[2][BM][BK];
    __shared__ __align__(16) bf16 Bs[2][BN][BK];
    const int tid = threadIdx.x;
    const int dir = blockIdx.z;
    const bool flip = FLIPD1 && (dir == 1);
    const bf16* Ad = A + (CATK ? (size_t)0 : (size_t)dir * Astr);
    const bf16* Bd = BT + (size_t)dir * Bstr;
    const int bm = blockIdx.y * BM, bn = blockIdx.x * BN;
    const int wave = tid >> 6, lane = tid & 63;
    const int wm = (wave >> 1) * (BM / 2), wn = (wave & 1) * (BN / 2);
    const int lm = lane & 15, lq = lane >> 4;
    const int lrow = lane >> 2, lcol = (lane & 3) * 8;  // 16 rows x 64B / wave
    f32x4 acc[FRm][FRn] = {};

    auto STAGE = [&](int buf, int k0) {
        const bf16* Ab = Ad;
        int ka = k0;
        if (CATK && k0 >= KH) { Ab = A + Astr; ka = k0 - KH; }
        const int kb = CATK ? (k0 & (KH - 1)) : k0;
#pragma unroll
        for (int c = 0; c < BM / 64; ++c) {
            int row = c * 64 + wave * 16 + lrow;
            int gm = bm + row;
            if (flip) gm = (gm & ~(LD - 1)) + (LD - 1 - (gm & (LD - 1)));
            glds16(Ab + (size_t)gm * lda + ka + lcol,
                   &As[buf][c * 64 + wave * 16][0]);
        }
#pragma unroll
        for (int c = 0; c < BN / 64; ++c) {
            int row = c * 64 + wave * 16 + lrow;
            glds16(Bd + (size_t)(bn + row) * ldb + kb + lcol,
                   &Bs[buf][c * 64 + wave * 16][0]);
        }
    };
    auto COMPUTE = [&](int buf) {
        bf16x8 af[FRm], bfr[FRn];
#pragma unroll
        for (int i = 0; i < FRm; ++i)
            af[i] = *(const bf16x8*)&As[buf][wm + 16 * i + lm][lq * 8];
#pragma unroll
        for (int j = 0; j < FRn; ++j)
            bfr[j] = *(const bf16x8*)&Bs[buf][wn + 16 * j + lm][lq * 8];
#pragma unroll
        for (int i = 0; i < FRm; ++i)
#pragma unroll
            for (int j = 0; j < FRn; ++j)
                acc[i][j] = __builtin_amdgcn_mfma_f32_16x16x32_bf16(
                    af[i], bfr[j], acc[i][j], 0, 0, 0);
    };

    STAGE(0, 0);                    // NC loads in flight
    int cur = 0;
    for (int k0 = BK; k0 < K; k0 += BK) {
        STAGE(cur ^ 1, k0);         // +NC -> 2*NC in flight
        vmw_<NC>();                 // oldest NC (current tile) landed, this wave
        bar_();                     // ...landed for ALL waves
        COMPUTE(cur);               // next tile's loads still flying underneath
        bar_();                     // all reads of buf done before reuse
        cur ^= 1;
    }
    vmw_<0>();
    bar_();
    COMPUTE(cur);

    bf16* Cd = (MODE == 5) ? nullptr : Cb + (size_t)dir * Cstr;
#pragma unroll
    for (int i = 0; i < FRm; ++i) {
#pragma unroll
        for (int j = 0; j < FRn; ++j) {
            int col = bn + wn + 16 * j + lm;
            float bv = (MODE == 2) ? bias[col]
                     : (MODE == 5) ? 2.f * bias[col] : 0.f;
#pragma unroll
            for (int r = 0; r < 4; ++r) {
                int row = bm + wm + 16 * i + lq * 4 + r;
                float v = acc[i][j][r] + bv;
                size_t idx = (size_t)row * ldc + col;
                if (MODE == 0)      Cd[idx] = __float2bfloat16(v);
                else if (MODE == 2) Cd[idx] = __float2bfloat16(fmaxf(v, 0.f));
                else {
                    float m2 = __bfloat162float(mp[idx])
                             + __bfloat162float(mp[mpStr + idx]);
                    outp[idx] = v + m2;
                }
            }
        }
    }
}

// ---------------- zgate3: yrow = silu(x(flip?) @ inw_z) * y2t^T --------------
// (round-26 winner, verbatim)
__global__ __launch_bounds__(256)
void zgate3_k(const bf16* __restrict__ xbf, const bf16* __restrict__ inwT,
              const bf16* __restrict__ y2t_all, bf16* __restrict__ yrow_all)
{
    __shared__ __align__(16) char smem[24576];   // As 8KB | Bs 16KB ; sy aliases
    bf16 (*As)[64] = (bf16(*)[64])smem;              // [64][64]
    bf16 (*Bs)[64] = (bf16(*)[64])(smem + 8192);     // [128][64]
    __bf16 (*sy)[74] = (__bf16(*)[74])smem;          // [128][74] = 18.5KB alias
    const int tid = threadIdx.x;
    const int dir = blockIdx.z;
    const bf16* Bd = inwT + (size_t)dir * (2048 * 512) + (size_t)1024 * 512;
    const bf16* y2t = y2t_all + (size_t)dir * ((size_t)MROWS * EDIM);
    bf16* yrow = yrow_all + (size_t)dir * ((size_t)MROWS * EDIM);
    const int bm = blockIdx.y * 64, bn = blockIdx.x * 128;
    const int wave = tid >> 6, lane = tid & 63;
    const int wm = (wave >> 1) * 32, wn = (wave & 1) * 64;
    const int lm = lane & 15, lq = lane >> 4;
    const int lrow = lane >> 3, lcol = (lane & 7) * 8;
    f32x4 acc[2][4] = {};

    for (int k0 = 0; k0 < 512; k0 += 64) {
#pragma unroll
        for (int c = 0; c < 2; ++c) {
            int row = c * 32 + wave * 8 + lrow;
            int gm = bm + row;
            if (dir == 1) gm = (gm & ~(LD - 1)) + (LD - 1 - (gm & (LD - 1)));
            glds16(xbf + (size_t)gm * 512 + k0 + lcol, &As[c * 32 + wave * 8][0]);
        }
#pragma unroll
        for (int c = 0; c < 4; ++c) {
            int row = c * 32 + wave * 8 + lrow;
            glds16(Bd + (size_t)(bn + row) * 512 + k0 + lcol,
                   &Bs[c * 32 + wave * 8][0]);
        }
        __syncthreads();
#pragma unroll
        for (int kh = 0; kh < 2; ++kh) {
            bf16x8 af[2], bfr[4];
#pragma unroll
            for (int i = 0; i < 2; ++i)
                af[i] = *(const bf16x8*)&As[wm + 16 * i + lm][kh * 32 + lq * 8];
#pragma unroll
            for (int j = 0; j < 4; ++j)
                bfr[j] = *(const bf16x8*)&Bs[wn + 16 * j + lm][kh * 32 + lq * 8];
#pragma unroll
            for (int i = 0; i < 2; ++i)
#pragma unroll
                for (int j = 0; j < 4; ++j)
                    acc[i][j] = __builtin_amdgcn_mfma_f32_16x16x32_bf16(
                        af[i], bfr[j], acc[i][j], 0, 0, 0);
        }
        __syncthreads();   // last iter: As/Bs now dead -> sy may alias
    }

    {
        const int b = bm >> 11, l0 = bm & (LD - 1);
        int e = tid >> 1, lh = (tid & 1) * 32;
        const bf16* yp = y2t + ((size_t)b * EDIM + bn + e) * LD + l0 + lh;
#pragma unroll
        for (int i = 0; i < 4; ++i)
            *(bf16x8*)&sy[e][lh + i * 8] = *(const bf16x8*)(yp + i * 8);
    }
    __syncthreads();
#pragma unroll
    for (int i = 0; i < 2; ++i) {
#pragma unroll
        for (int j = 0; j < 4; ++j) {
            int col = bn + wn + 16 * j + lm;
#pragma unroll
            for (int r = 0; r < 4; ++r) {
                int row = bm + wm + 16 * i + lq * 4 + r;
                float z = acc[i][j][r];
                float g = z * sig_(z);
                float y = (float)sy[col - bn][row - bm];
                yrow[(size_t)row * EDIM + col] = __float2bfloat16(g * y);
            }
        }
    }
}

// ---------------- conv3: glds16-staged conv(4)+bias+silu+transpose ----------
__global__ __launch_bounds__(256)
void conv3_k(const bf16* __restrict__ xs2,
             const float* __restrict__ cw_f, const float* __restrict__ cb_f,
             const float* __restrict__ cw_b, const float* __restrict__ cb_b,
             bf16* __restrict__ xct2)
{
    __shared__ __align__(16) __bf16 sxs[72][64];   // 9.2KB
    __shared__ float sout[64][65];                 // 16.6KB
    const int tid = threadIdx.x;
    const int dir = blockIdx.z;
    const bf16* xs = xs2 + (size_t)dir * ((size_t)MROWS * EDIM);
    const float* w  = dir ? cw_b : cw_f;
    const float* cb = dir ? cb_b : cb_f;
    bf16* xct = xct2 + (size_t)dir * ((size_t)MROWS * EDIM);
    const int e0 = blockIdx.x * 64;
    const int bl0 = blockIdx.y * 64;
    const int lloc0 = bl0 & (LD - 1);
    const int b = bl0 >> 11;
    const int wave = tid >> 6, lane = tid & 63;

    for (int c = wave; c < 9; c += 4) {
        int g = bl0 - 8 + c * 8 + (lane >> 3);
        glds16(xs + (size_t)g * EDIM + e0 + (lane & 7) * 8, &sxs[c * 8][0]);
    }
    __syncthreads();
    if (lloc0 == 0 && tid < 192)
        sxs[5 + (tid >> 6)][tid & 63] = (__bf16)0.f;
    __syncthreads();

    {
        int lr4 = tid >> 6, e = tid & 63;
        float w0 = w[(e0 + e) * 4 + 0], w1 = w[(e0 + e) * 4 + 1];
        float w2 = w[(e0 + e) * 4 + 2], w3 = w[(e0 + e) * 4 + 3];
        float cbv = cb[e0 + e];
#pragma unroll
        for (int i = 0; i < 16; ++i) {
            int lr = i * 4 + lr4;
            float acc = cbv;
            acc = fmaf((float)sxs[lr + 5][e], w0, acc);
            acc = fmaf((float)sxs[lr + 6][e], w1, acc);
            acc = fmaf((float)sxs[lr + 7][e], w2, acc);
            acc = fmaf((float)sxs[lr + 8][e], w3, acc);
            sout[e][lr] = acc * sig_(acc);
        }
    }
    __syncthreads();
    {
        int l8 = (tid & 7) * 8;
#pragma unroll
        for (int i = 0; i < 2; ++i) {
            int er = i * 32 + (tid >> 3);
            bf16x8 o;
#pragma unroll
            for (int j = 0; j < 8; ++j) o[j] = (__bf16)sout[er][l8 + j];
            *(bf16x8*)(xct + ((size_t)b * EDIM + e0 + er) * LD + lloc0 + l8) = o;
        }
    }
}

// ---------------- g2m2: MFMA dbl = xc @ xproj, BM=32, BK=64 ------------------
__global__ __launch_bounds__(256)
void g2m2_k(const bf16* __restrict__ xct2, const bf16* __restrict__ xpT2,
            float* __restrict__ dblt2, float* __restrict__ dbldt2)
{
    __shared__ float As[32][68];            // [l][e] transposed f32, 8.7KB
    __shared__ __align__(16) bf16 Bs[64][64];   // 8KB
    __shared__ float sDT[32][33];           // dt cols [l][n]
    __shared__ float sBC[32][33];           // BC cols [n-32][l]
    const int tid = threadIdx.x;
    const int dir = blockIdx.z;
    const bf16* xct = xct2 + (size_t)dir * ((size_t)MROWS * EDIM);
    const bf16* xpT = xpT2 + (size_t)dir * (64 * 1024);
    float* dblt = dblt2 + (size_t)dir * (2 * 64 * LD);
    float* dbldt = dbldt2 + (size_t)dir * (2 * 2048 * DTR);
    const int bm = blockIdx.y * 32;
    const int bB = bm >> 11, l0 = bm & (LD - 1);
    const int wave = tid >> 6, lane = tid & 63;
    const int wml = (wave >> 1) * 16, wnn = (wave & 1) * 32;
    const int lm = lane & 15, lq = lane >> 4;
    const int er = tid >> 2, l8 = (tid & 3) * 8;   // A-stage: 64 e x 32 l
    const int lrow = lane >> 3, lcol = (lane & 7) * 8;
    f32x4 acc[2] = {};

    for (int k0 = 0; k0 < EDIM; k0 += 64) {
#pragma unroll
        for (int c = 0; c < 2; ++c) {
            int row = c * 32 + wave * 8 + lrow;
            glds16(xpT + (size_t)row * 1024 + k0 + lcol, &Bs[c * 32 + wave * 8][0]);
        }
        {
            bf16x8 v = *(const bf16x8*)(xct +
                ((size_t)bB * EDIM + k0 + er) * LD + l0 + l8);
#pragma unroll
            for (int j = 0; j < 8; ++j) As[l8 + j][er] = (float)v[j];
        }
        __syncthreads();
#pragma unroll
        for (int kh = 0; kh < 2; ++kh) {
            bf16x8 af;
#pragma unroll
            for (int j = 0; j < 8; ++j)
                af[j] = (__bf16)As[wml + lm][kh * 32 + lq * 8 + j];
#pragma unroll
            for (int j = 0; j < 2; ++j) {
                bf16x8 bfr = *(const bf16x8*)&Bs[wnn + 16 * j + lm][kh * 32 + lq * 8];
                acc[j] = __builtin_amdgcn_mfma_f32_16x16x32_bf16(af, bfr, acc[j], 0, 0, 0);
            }
        }
        __syncthreads();
    }
    if (wnn == 0) {
#pragma unroll
        for (int j = 0; j < 2; ++j) {
            int col = 16 * j + lm;
#pragma unroll
            for (int r = 0; r < 4; ++r)
                sDT[wml + lq * 4 + r][col] = acc[j][r];
        }
    } else {
#pragma unroll
        for (int j = 0; j < 2; ++j) {
            int col = 16 * j + lm;
#pragma unroll
            for (int r = 0; r < 4; ++r)
                sBC[col][wml + lq * 4 + r] = acc[j][r];
        }
    }
    __syncthreads();
    {
        int row = tid >> 3, c4 = (tid & 7) * 4;
        float4 v = make_float4(sDT[row][c4], sDT[row][c4 + 1],
                               sDT[row][c4 + 2], sDT[row][c4 + 3]);
        *(float4*)(dbldt + (size_t)(bB * 2048 + l0 + row) * DTR + c4) = v;
    }
    {
        int nr = tid >> 3, ll = (tid & 7) * 4;
        float4 v = make_float4(sBC[nr][ll], sBC[nr][ll + 1],
                               sBC[nr][ll + 2], sBC[nr][ll + 3]);
        *(float4*)(dblt + (size_t)(bB * 64 + 32 + nr) * LD + l0 + ll) = v;
    }
}

// ---------------- g3m: MFMA dlt_t = softplus(dbldt @ dtw + b)^T --------------
__global__ __launch_bounds__(256)
void g3m_k(const float* __restrict__ dbldt2, const bf16* __restrict__ dtwT2,
           const float* __restrict__ dtb_f, const float* __restrict__ dtb_b,
           bf16* __restrict__ dltt2)
{
    __shared__ __align__(16) bf16 As[64][40];
    __shared__ __align__(16) bf16 Bs[64][32];
    __shared__ float sC[64][65];
    const int tid = threadIdx.x;
    const int dir = blockIdx.z;
    const float* Ap = dbldt2 + (size_t)dir * (2 * 2048 * DTR);
    const bf16* BT = dtwT2 + (size_t)dir * (1024 * DTR);
    const float* bias = dir ? dtb_b : dtb_f;
    bf16* dltt = dltt2 + (size_t)dir * ((size_t)MROWS * EDIM);
    const int bm = blockIdx.y * 64, bn = blockIdx.x * 64;
    const int bB = bm >> 11, l0 = bm & (LD - 1);
    const int wave = tid >> 6, lane = tid & 63;
    const int wm = (wave >> 1) * 32, wn = (wave & 1) * 32;
    const int lm = lane & 15, lq = lane >> 4;

    {
        int row = tid >> 2, c8 = (tid & 3) * 8;
        const float* p = Ap + (size_t)(bB * 2048 + l0 + row) * DTR + c8;
        float4 v0 = *(const float4*)p, v1 = *(const float4*)(p + 4);
        bf16x8 o;
        o[0]=(__bf16)v0.x; o[1]=(__bf16)v0.y; o[2]=(__bf16)v0.z; o[3]=(__bf16)v0.w;
        o[4]=(__bf16)v1.x; o[5]=(__bf16)v1.y; o[6]=(__bf16)v1.z; o[7]=(__bf16)v1.w;
        *(bf16x8*)&As[row][c8] = o;
    }
    glds16(BT + (size_t)(bn + wave * 16 + (lane >> 2)) * DTR + (lane & 3) * 8,
           &Bs[wave * 16][0]);
    __syncthreads();

    bf16x8 af[2], bfr[2];
#pragma unroll
    for (int i = 0; i < 2; ++i)
        af[i] = *(const bf16x8*)&As[wm + 16 * i + lm][lq * 8];
#pragma unroll
    for (int j = 0; j < 2; ++j)
        bfr[j] = *(const bf16x8*)&Bs[wn + 16 * j + lm][lq * 8];
    f32x4 acc[2][2] = {};
#pragma unroll
    for (int i = 0; i < 2; ++i)
#pragma unroll
        for (int j = 0; j < 2; ++j)
            acc[i][j] = __builtin_amdgcn_mfma_f32_16x16x32_bf16(
                af[i], bfr[j], acc[i][j], 0, 0, 0);

#pragma unroll
    for (int i = 0; i < 2; ++i)
#pragma unroll
        for (int j = 0; j < 2; ++j) {
            int col = wn + 16 * j + lm;
            float bv = bias[bn + col];
#pragma unroll
            for (int r = 0; r < 4; ++r) {
                int row = wm + 16 * i + lq * 4 + r;
                float v = acc[i][j][r] + bv;
                v = (v > 20.f) ? v : log1pf(__expf(v));
                sC[col][row] = v;
            }
        }
    __syncthreads();
    {
        int erow = tid >> 2, l16 = (tid & 3) * 16;
        bf16* d = dltt + ((size_t)bB * EDIM + bn + erow) * LD + l0 + l16;
#pragma unroll
        for (int h = 0; h < 2; ++h) {
            bf16x8 o;
#pragma unroll
            for (int j = 0; j < 8; ++j) o[j] = (__bf16)sC[erow][l16 + h * 8 + j];
            *(bf16x8*)(d + h * 8) = o;
        }
    }
}

// ---------------- scan6 dir-merged: 256 chunks x 8 steps, parallel scan ------
__global__ __launch_bounds__(256)
void scan6_k(bf16* __restrict__ xct2, const bf16* __restrict__ dltt2,
             const float* __restrict__ dblt2,
             const float* __restrict__ alog_f, const float* __restrict__ alog_b,
             const float* __restrict__ dp_f, const float* __restrict__ dp_b)
{
    __shared__ float sA[NST];
    __shared__ float sWp[NST][4];
    __shared__ float sWs[NST][4];
    const int gid = blockIdx.x;                 // 0..4095
    const int dir = gid >> 11;
    const int bb  = (gid >> 10) & 1;
    const int e   = gid & (EDIM - 1);
    const float* A_log = dir ? alog_b : alog_f;
    const float* Dp    = dir ? dp_b   : dp_f;
    bf16* xct = xct2 + (size_t)dir * ((size_t)MROWS * EDIM);
    const bf16* dltt = dltt2 + (size_t)dir * ((size_t)MROWS * EDIM);
    const float* bt = dblt2 + (size_t)dir * (2 * 64 * LD) + (size_t)bb * 64 * LD;
    const int tid = threadIdx.x;
    const int wave = tid >> 6, lane = tid & 63;
    const size_t baset = ((size_t)bb * EDIM + e) * LD;
    const int l0 = tid * 8;

    if (tid < NST) sA[tid] = -__expf(A_log[e * NST + tid]);

    float xv[8], dv[8], dx[8];
    {
        bf16x8 xr = *(const bf16x8*)(xct + baset + l0);
        bf16x8 dr = *(const bf16x8*)(dltt + baset + l0);
#pragma unroll
        for (int j = 0; j < 8; ++j) { xv[j] = (float)xr[j]; dv[j] = (float)dr[j]; }
    }
#pragma unroll
    for (int j = 0; j < 8; ++j) dx[j] = dv[j] * xv[j];
    __syncthreads();

    float y[8] = {};
    for (int n = 0; n < NST; ++n) {
        const float An = sA[n];
        const float* Bp = bt + (size_t)(DTR + n) * LD + l0;
        const float* Cp = bt + (size_t)(DTR + NST + n) * LD + l0;
        float4 b0 = *(const float4*)Bp, b1 = *(const float4*)(Bp + 4);
        float4 c0 = *(const float4*)Cp, c1 = *(const float4*)(Cp + 4);
        float Br[8] = {b0.x,b0.y,b0.z,b0.w, b1.x,b1.y,b1.z,b1.w};
        float Cr[8] = {c0.x,c0.y,c0.z,c0.w, c1.x,c1.y,c1.z,c1.w};

        float S[8], P[8];
        float h = 0.f, pr = 1.f;
#pragma unroll
        for (int l = 0; l < 8; ++l) {
            float a = __expf(dv[l] * An);
            pr *= a;
            h = fmaf(a, h, dx[l] * Br[l]);
            P[l] = pr; S[l] = h;
        }

        float p = pr, s = h;
#pragma unroll
        for (int d = 1; d < 64; d <<= 1) {
            float pp = __shfl_up(p, d, 64);
            float sp = __shfl_up(s, d, 64);
            if (lane >= d) { s = fmaf(sp, p, s); p *= pp; }
        }
        if (lane == 63) { sWp[n][wave] = p; sWs[n][wave] = s; }
        __syncthreads();
        float Hoff = 0.f;
#pragma unroll
        for (int w = 0; w < 3; ++w)
            if (w < wave) Hoff = fmaf(sWp[n][w], Hoff, sWs[n][w]);
        float pprev = __shfl_up(p, 1, 64);
        float sprev = __shfl_up(s, 1, 64);
        float H = (lane == 0) ? Hoff : fmaf(pprev, Hoff, sprev);

#pragma unroll
        for (int l = 0; l < 8; ++l)
            y[l] = fmaf(Cr[l], fmaf(P[l], H, S[l]), y[l]);
    }

    const float Dv = Dp[e];
    bf16x8 o;
#pragma unroll
    for (int l = 0; l < 8; ++l) o[l] = (__bf16)fmaf(xv[l], Dv, y[l]);
    *(bf16x8*)(xct + baset + l0) = o;
}

// ---------------- layernorm (bf16 in-place), dir0 rows only ------------------
__global__ __launch_bounds__(256)
void ln_k(bf16* __restrict__ m, const float* __restrict__ gg,
          const float* __restrict__ bb)
{
    int row = (blockIdx.x * 256 + threadIdx.x) >> 6;
    int lane = threadIdx.x & 63;
    bf16* r = m + (size_t)row * DMODEL;
    float v[8], s = 0.f, s2 = 0.f;
#pragma unroll
    for (int i = 0; i < 8; ++i) {
        v[i] = __bfloat162float(r[lane + 64 * i]);
        s += v[i]; s2 = fmaf(v[i], v[i], s2);
    }
#pragma unroll
    for (int off = 32; off >= 1; off >>= 1) {
        s  += __shfl_xor(s, off, 64);
        s2 += __shfl_xor(s2, off, 64);
    }
    float mu = s * (1.f / DMODEL);
    float var = s2 * (1.f / DMODEL) - mu * mu;
    float inv = rsqrtf(var + 1e-5f);
#pragma unroll
    for (int i = 0; i < 8; ++i)
        r[lane + 64 * i] = __float2bfloat16(
            (v[i] - mu) * inv * gg[lane + 64 * i] + bb[lane + 64 * i]);
}

__global__ void sentinel_k(float* __restrict__ o)
{
    int i = blockIdx.x * 256 + threadIdx.x;
    o[i] = 100.0f;
}

extern "C" void kernel_launch(void* const* d_in, const int* in_sizes, int n_in,
                              void* d_out, int out_size, void* d_ws, size_t ws_size,
                              hipStream_t stream)
{
    const float* x    = (const float*)d_in[0];
    const float* n1g  = (const float*)d_in[19];
    const float* n1b  = (const float*)d_in[20];
    const float* fw1  = (const float*)d_in[23];
    const float* fb1  = (const float*)d_in[24];
    const float* fw2  = (const float*)d_in[25];
    const float* fb2  = (const float*)d_in[26];
    float* out = (float*)d_out;

    const size_t MiB = 1024 * 1024;
    const size_t SZ_DM = (size_t)MROWS * DMODEL;
    if (ws_size < 49 * MiB) {
        sentinel_k<<<dim3(SZ_DM / 256), dim3(256), 0, stream>>>(out);
        return;
    }

    // ---- 48.4 MiB layout ----
    char* base = (char*)d_ws;
    bf16* fw1T  = (bf16*)base;                 // [1024][512]        1 MiB
    bf16* fw2T  = (bf16*)(base + 1 * MiB);     // [512][1024]        1 MiB
    bf16* outwT = (bf16*)(base + 2 * MiB);     // [2][512][1024]     2 MiB
    bf16* inwT  = (bf16*)(base + 4 * MiB);     // [2][2048][512]     4 MiB
    bf16* xbf   = (bf16*)(base + 8 * MiB);     // [4096][512]        4 MiB
    char* RA    = base + 12 * MiB;             // 16 MiB: xs2 -> dltt2 -> yrow2 -> ffh2
    bf16* xs2   = (bf16*)RA;                   // [2][4096][1024]
    bf16* dltt2 = (bf16*)RA;
    bf16* yrow2 = (bf16*)RA;
    bf16* ffh2  = (bf16*)RA;
    char* RB    = base + 28 * MiB;             // 16 MiB: xct2 -> mbf2
    bf16* xct2  = (bf16*)RB;                   // [2][2][1024][2048]
    bf16* mbf2  = (bf16*)RB;                   // [2][4096][512]
    float* dblt2 = (float*)(base + 44 * MiB);  // [2][2][64][2048]   2 MiB (rows 32..63 used)
    float* dbldt2 = (float*)(base + 46 * MiB); // [2][2][2048][32]   2 MiB
    bf16* xpT2  = (bf16*)(base + 48 * MiB);               // [2][64][1024]  256 KiB
    bf16* dtwT2 = (bf16*)(base + 48 * MiB + 256 * 1024);  // [2][1024][32]  128 KiB

    const float* inw_f  = (const float*)d_in[1];
    const float* cw_f   = (const float*)d_in[2];
    const float* cb_f   = (const float*)d_in[3];
    const float* xp_f   = (const float*)d_in[4];
    const float* dtw_f  = (const float*)d_in[5];
    const float* dtb_f  = (const float*)d_in[6];
    const float* alog_f = (const float*)d_in[7];
    const float* dp_f   = (const float*)d_in[8];
    const float* outw_f = (const float*)d_in[9];
    const float* inw_b  = (const float*)d_in[10];
    const float* cw_b   = (const float*)d_in[11];
    const float* cb_b   = (const float*)d_in[12];
    const float* xp_b   = (const float*)d_in[13];
    const float* dtw_b  = (const float*)d_in[14];
    const float* dtb_b  = (const float*)d_in[15];
    const float* alog_b = (const float*)d_in[16];
    const float* dp_b   = (const float*)d_in[17];
    const float* outw_b = (const float*)d_in[18];

    dim3 blk(256);
    const size_t U = (size_t)MROWS * EDIM;   // 4,194,304 elems

    // 1. prep: all transposes + xconv
    prep_k<<<dim3(6336), blk, 0, stream>>>(x, xbf, inw_f, inw_b, inwT,
                                           outw_f, outw_b, outwT,
                                           fw1, fw1T, fw2, fw2T,
                                           xp_f, xp_b, xpT2,
                                           dtw_f, dtw_b, dtwT2);
    // 2. G1: xs2[dir] = x(flip d1) @ in_w[:, :1024]   M=4096 N=1024 K=512
    bgemm5_k<128, 64, 0, true, false><<<dim3(16, 32, 2), blk, 0, stream>>>(
        xbf, 0, DMODEL, inwT, (size_t)2048 * 512, DMODEL, nullptr,
        xs2, U, EDIM, nullptr, 0, nullptr, DMODEL);
    // 3. conv + silu + transpose (glds16-staged)
    conv3_k<<<dim3(16, 64, 2), blk, 0, stream>>>(xs2, cw_f, cb_f, cw_b, cb_b, xct2);
    // 4. G2 (MFMA): dblt rows 32..63 + dbldt row-major  (BM=32, BK=64)
    g2m2_k<<<dim3(1, 128, 2), blk, 0, stream>>>(xct2, xpT2, dblt2, dbldt2);
    // 5. G3 (MFMA): dltt2 (over dead xs2)
    g3m_k<<<dim3(16, 64, 2), blk, 0, stream>>>(dbldt2, dtwT2, dtb_f, dtb_b, dltt2);
    // 6. scan (in-place over xct2) — scan6 verbatim
    scan6_k<<<dim3(4096), blk, 0, stream>>>(xct2, dltt2, dblt2,
                                            alog_f, alog_b, dp_f, dp_b);
    // 7. zgate3: yrow2 = silu(x @ inw_z) * y  (writes over dead dltt2)
    zgate3_k<<<dim3(8, 64, 2), blk, 0, stream>>>(xbf, inwT, xct2, yrow2);
    // 8. G4: mbf2[dir] = y @ out_w   M=4096 N=512 K=1024
    bgemm5_k<64, 64, 0, false, false><<<dim3(8, 64, 2), blk, 0, stream>>>(
        yrow2, U, EDIM, outwT, (size_t)512 * 1024, EDIM, nullptr,
        mbf2, SZ_DM, DMODEL, nullptr, 0, nullptr, EDIM);
    // 9. LN on dir0 half of mbf2 (in place)
    ln_k<<<dim3(MROWS / 4), blk, 0, stream>>>(mbf2, n1g, n1b);
    // 10. G5: ffh2[dir] = relu(m @ fw1 + fb1)   M=4096 N=1024 K=512
    bgemm5_k<128, 64, 2, false, false><<<dim3(16, 32, 2), blk, 0, stream>>>(
        mbf2, SZ_DM, DMODEL, fw1T, 0, DMODEL, fb1,
        ffh2, U, DFF, nullptr, 0, nullptr, DMODEL);
    // 11. G6 fused (concat-K): out = ffh_f@fw2 + ffh_b@fw2 + 2*fb2 + m_f + m_b
    bgemm5_k<64, 64, 5, false, true><<<dim3(8, 64, 1), blk, 0, stream>>>(
        ffh2, U, DFF, fw2T, 0, DFF, fb2,
        nullptr, 0, DMODEL, mbf2, SZ_DM, out, 2 * DFF);
}

// Round 15
// 343.629 us; speedup vs baseline: 1.0238x; 1.0238x over previous
//
#include <hip/hip_runtime.h>
#include <hip/hip_bf16.h>
#include <math.h>

// BiMambaEncoderLayer: B=2, L=2048, D_MODEL=512, ED=1024, N=16, DCONV=4,
// DT_RANK=32, D_FF=1024. f32 in/out.
// Round-30: REVERT to the round-27 winner (344.4us, bracketed by 345.2 and
// 351.8). Round-29's counted-vmcnt BK=32 pipeline regressed (+7.4us): at
// 16 MFMA/step the per-step compute (~130cy) can't cover load latency with
// only 2-deep prefetch, and 2 barriers/step double the sync cost. BK=64
// single-buffer stands as the measured optimum for these small-K shapes
// (5 schedule variants probed). Config: bgemm4 BK=64 single-buffer
// (G1/G5 128x128, G4 128x64, G6 64x64 concat-K), conv3 glds16, zgate3
// LDS-alias, g2m BM=32, g3m, scan6, ln, prep. 11 dispatches, 48.4 MiB ws.

#define BD 2
#define LD 2048
#define DMODEL 512
#define EDIM 1024
#define NST 16
#define DTR 32
#define DFF 1024
#define MROWS (BD*LD)   // 4096

typedef __hip_bfloat16 bf16;
typedef __bf16 bf16x8 __attribute__((ext_vector_type(8)));
typedef __bf16 bf16x4 __attribute__((ext_vector_type(4)));
typedef float  f32x4  __attribute__((ext_vector_type(4)));

__device__ __forceinline__ float sig_(float x) { return 1.f / (1.f + __expf(-x)); }

// async 16B global->LDS (wave-uniform LDS base, per-lane global addr)
__device__ __forceinline__ void glds16(const void* g, void* l)
{
    __builtin_amdgcn_global_load_lds(
        (const __attribute__((address_space(1))) void*)g,
        (__attribute__((address_space(3))) void*)l, 16, 0, 0);
}

// ---------------- prep: all weight transposes + x->bf16, one dispatch --------
// [0,2048) xconv | [2048,4096) inwT | [4096,5120) outwT | [5120,5632) fw1T |
// [5632,6144) fw2T | [6144,6272) xpT | [6272,6336) dtwT
__global__ __launch_bounds__(256)
void prep_k(const float* __restrict__ x, bf16* __restrict__ xbf,
            const float* __restrict__ inw_f, const float* __restrict__ inw_b,
            bf16* __restrict__ inwT,
            const float* __restrict__ outw_f, const float* __restrict__ outw_b,
            bf16* __restrict__ outwT,
            const float* __restrict__ fw1, bf16* __restrict__ fw1T,
            const float* __restrict__ fw2, bf16* __restrict__ fw2T,
            const float* __restrict__ xp_f, const float* __restrict__ xp_b,
            bf16* __restrict__ xpT,
            const float* __restrict__ dtw_f, const float* __restrict__ dtw_b,
            bf16* __restrict__ dtwT)
{
    const int bid = blockIdx.x, tid = threadIdx.x;
    if (bid < 2048) {
        size_t i = (size_t)bid * 1024 + tid * 4;
        float4 v = *(const float4*)(x + i);
        bf16* o = xbf + i;
        o[0] = __float2bfloat16(v.x); o[1] = __float2bfloat16(v.y);
        o[2] = __float2bfloat16(v.z); o[3] = __float2bfloat16(v.w);
        return;
    }
    const float* W; bf16* WT; int R, C, cx, ry;
    if (bid < 4096) {
        int d = (bid - 2048) >> 10, t = (bid - 2048) & 1023;
        W = d ? inw_b : inw_f; WT = inwT + (size_t)d * 2048 * 512;
        R = 512; C = 2048; cx = t & 63; ry = t >> 6;
    } else if (bid < 5120) {
        int d = (bid - 4096) >> 9, t = (bid - 4096) & 511;
        W = d ? outw_b : outw_f; WT = outwT + (size_t)d * 512 * 1024;
        R = 1024; C = 512; cx = t & 15; ry = t >> 4;
    } else if (bid < 5632) {
        int t = bid - 5120; W = fw1; WT = fw1T; R = 512; C = 1024;
        cx = t & 31; ry = t >> 5;
    } else if (bid < 6144) {
        int t = bid - 5632; W = fw2; WT = fw2T; R = 1024; C = 512;
        cx = t & 15; ry = t >> 4;
    } else if (bid < 6272) {
        int d = (bid - 6144) >> 6, t = (bid - 6144) & 63;
        W = d ? xp_b : xp_f; WT = xpT + (size_t)d * 64 * 1024;
        R = 1024; C = 64; cx = t & 1; ry = t >> 1;
    } else {
        int d = (bid - 6272) >> 5, t = (bid - 6272) & 31;
        W = d ? dtw_b : dtw_f; WT = dtwT + (size_t)d * 1024 * DTR;
        R = 32; C = 1024; cx = t; ry = 0;
    }
    __shared__ float tt[32][33];
    const int c0 = cx * 32, r0 = ry * 32;
    const int col = tid & 31, rr = tid >> 5;
#pragma unroll
    for (int p = 0; p < 4; ++p)
        tt[p * 8 + rr][col] = W[(size_t)(r0 + p * 8 + rr) * C + c0 + col];
    __syncthreads();
#pragma unroll
    for (int p = 0; p < 4; ++p)
        WT[(size_t)(c0 + p * 8 + rr) * R + r0 + col] =
            __float2bfloat16(tt[col][p * 8 + rr]);
}

// ---------------- bgemm4: BMxBN MFMA GEMM, BK=64, single-buffer -------------
template<int BM, int BN, int MODE, bool FLIPD1, bool CATK>
__global__ __launch_bounds__(256)
void bgemm4_k(const bf16* __restrict__ A, size_t Astr, int lda,
              const bf16* __restrict__ BT, size_t Bstr, int ldb,
              const float* __restrict__ bias,
              bf16* __restrict__ Cb, size_t Cstr, int ldc,
              const bf16* __restrict__ mp, size_t mpStr,
              float* __restrict__ outp, int K)
{
    constexpr int BK = 64;
    constexpr int FRm = BM / 32, FRn = BN / 32;
    constexpr int KH = DFF;   // concat-K half length (1024)
    __shared__ __align__(16) bf16 As[BM][BK];
    __shared__ __align__(16) bf16 Bs[BN][BK];
    const int tid = threadIdx.x;
    const int dir = blockIdx.z;
    const bool flip = FLIPD1 && (dir == 1);
    const bf16* Ad = A + (CATK ? (size_t)0 : (size_t)dir * Astr);
    const bf16* Bd = BT + (size_t)dir * Bstr;
    const int bm = blockIdx.y * BM, bn = blockIdx.x * BN;
    const int wave = tid >> 6, lane = tid & 63;
    const int wm = (wave >> 1) * (BM / 2), wn = (wave & 1) * (BN / 2);
    const int lm = lane & 15, lq = lane >> 4;
    const int lrow = lane >> 3, lcol = (lane & 7) * 8;   // 8 rows x 128B / wave
    f32x4 acc[FRm][FRn] = {};

    for (int k0 = 0; k0 < K; k0 += BK) {
        const bf16* Ab = Ad;
        int ka = k0;
        if (CATK && k0 >= KH) { Ab = A + Astr; ka = k0 - KH; }
        const int kb = CATK ? (k0 & (KH - 1)) : k0;
#pragma unroll
        for (int c = 0; c < BM / 32; ++c) {
            int row = c * 32 + wave * 8 + lrow;
            int gm = bm + row;
            if (flip) gm = (gm & ~(LD - 1)) + (LD - 1 - (gm & (LD - 1)));
            glds16(Ab + (size_t)gm * lda + ka + lcol,
                   &As[c * 32 + wave * 8][0]);
        }
#pragma unroll
        for (int c = 0; c < BN / 32; ++c) {
            int row = c * 32 + wave * 8 + lrow;
            glds16(Bd + (size_t)(bn + row) * ldb + kb + lcol,
                   &Bs[c * 32 + wave * 8][0]);
        }
        __syncthreads();   // drains vmcnt -> staging complete

#pragma unroll
        for (int kh = 0; kh < 2; ++kh) {
            bf16x8 af[FRm], bfr[FRn];
#pragma unroll
            for (int i = 0; i < FRm; ++i)
                af[i] = *(const bf16x8*)&As[wm + 16 * i + lm][kh * 32 + lq * 8];
#pragma unroll
            for (int j = 0; j < FRn; ++j)
                bfr[j] = *(const bf16x8*)&Bs[wn + 16 * j + lm][kh * 32 + lq * 8];
#pragma unroll
            for (int i = 0; i < FRm; ++i)
#pragma unroll
                for (int j = 0; j < FRn; ++j)
                    acc[i][j] = __builtin_amdgcn_mfma_f32_16x16x32_bf16(
                        af[i], bfr[j], acc[i][j], 0, 0, 0);
        }
        __syncthreads();
    }

    bf16* Cd = (MODE == 5) ? nullptr : Cb + (size_t)dir * Cstr;
#pragma unroll
    for (int i = 0; i < FRm; ++i) {
#pragma unroll
        for (int j = 0; j < FRn; ++j) {
            int col = bn + wn + 16 * j + lm;
            float bv = (MODE == 2) ? bias[col]
                     : (MODE == 5) ? 2.f * bias[col] : 0.f;
#pragma unroll
            for (int r = 0; r < 4; ++r) {
                int row = bm + wm + 16 * i + lq * 4 + r;
                float v = acc[i][j][r] + bv;
                size_t idx = (size_t)row * ldc + col;
                if (MODE == 0)      Cd[idx] = __float2bfloat16(v);
                else if (MODE == 2) Cd[idx] = __float2bfloat16(fmaxf(v, 0.f));
                else {
                    float m2 = __bfloat162float(mp[idx])
                             + __bfloat162float(mp[mpStr + idx]);
                    outp[idx] = v + m2;
                }
            }
        }
    }
}

// ---------------- zgate3: yrow = silu(x(flip?) @ inw_z) * y2t^T --------------
__global__ __launch_bounds__(256)
void zgate3_k(const bf16* __restrict__ xbf, const bf16* __restrict__ inwT,
              const bf16* __restrict__ y2t_all, bf16* __restrict__ yrow_all)
{
    __shared__ __align__(16) char smem[24576];   // As 8KB | Bs 16KB ; sy aliases
    bf16 (*As)[64] = (bf16(*)[64])smem;              // [64][64]
    bf16 (*Bs)[64] = (bf16(*)[64])(smem + 8192);     // [128][64]
    __bf16 (*sy)[74] = (__bf16(*)[74])smem;          // [128][74] = 18.5KB alias
    const int tid = threadIdx.x;
    const int dir = blockIdx.z;
    const bf16* Bd = inwT + (size_t)dir * (2048 * 512) + (size_t)1024 * 512;
    const bf16* y2t = y2t_all + (size_t)dir * ((size_t)MROWS * EDIM);
    bf16* yrow = yrow_all + (size_t)dir * ((size_t)MROWS * EDIM);
    const int bm = blockIdx.y * 64, bn = blockIdx.x * 128;
    const int wave = tid >> 6, lane = tid & 63;
    const int wm = (wave >> 1) * 32, wn = (wave & 1) * 64;
    const int lm = lane & 15, lq = lane >> 4;
    const int lrow = lane >> 3, lcol = (lane & 7) * 8;
    f32x4 acc[2][4] = {};

    for (int k0 = 0; k0 < 512; k0 += 64) {
#pragma unroll
        for (int c = 0; c < 2; ++c) {
            int row = c * 32 + wave * 8 + lrow;
            int gm = bm + row;
            if (dir == 1) gm = (gm & ~(LD - 1)) + (LD - 1 - (gm & (LD - 1)));
            glds16(xbf + (size_t)gm * 512 + k0 + lcol, &As[c * 32 + wave * 8][0]);
        }
#pragma unroll
        for (int c = 0; c < 4; ++c) {
            int row = c * 32 + wave * 8 + lrow;
            glds16(Bd + (size_t)(bn + row) * 512 + k0 + lcol,
                   &Bs[c * 32 + wave * 8][0]);
        }
        __syncthreads();
#pragma unroll
        for (int kh = 0; kh < 2; ++kh) {
            bf16x8 af[2], bfr[4];
#pragma unroll
            for (int i = 0; i < 2; ++i)
                af[i] = *(const bf16x8*)&As[wm + 16 * i + lm][kh * 32 + lq * 8];
#pragma unroll
            for (int j = 0; j < 4; ++j)
                bfr[j] = *(const bf16x8*)&Bs[wn + 16 * j + lm][kh * 32 + lq * 8];
#pragma unroll
            for (int i = 0; i < 2; ++i)
#pragma unroll
                for (int j = 0; j < 4; ++j)
                    acc[i][j] = __builtin_amdgcn_mfma_f32_16x16x32_bf16(
                        af[i], bfr[j], acc[i][j], 0, 0, 0);
        }
        __syncthreads();   // last iter: As/Bs now dead -> sy may alias
    }

    {
        const int b = bm >> 11, l0 = bm & (LD - 1);
        int e = tid >> 1, lh = (tid & 1) * 32;
        const bf16* yp = y2t + ((size_t)b * EDIM + bn + e) * LD + l0 + lh;
#pragma unroll
        for (int i = 0; i < 4; ++i)
            *(bf16x8*)&sy[e][lh + i * 8] = *(const bf16x8*)(yp + i * 8);
    }
    __syncthreads();
#pragma unroll
    for (int i = 0; i < 2; ++i) {
#pragma unroll
        for (int j = 0; j < 4; ++j) {
            int col = bn + wn + 16 * j + lm;
#pragma unroll
            for (int r = 0; r < 4; ++r) {
                int row = bm + wm + 16 * i + lq * 4 + r;
                float z = acc[i][j][r];
                float g = z * sig_(z);
                float y = (float)sy[col - bn][row - bm];
                yrow[(size_t)row * EDIM + col] = __float2bfloat16(g * y);
            }
        }
    }
}

// ---------------- conv3: glds16-staged conv(4)+bias+silu+transpose ----------
__global__ __launch_bounds__(256)
void conv3_k(const bf16* __restrict__ xs2,
             const float* __restrict__ cw_f, const float* __restrict__ cb_f,
             const float* __restrict__ cw_b, const float* __restrict__ cb_b,
             bf16* __restrict__ xct2)
{
    __shared__ __align__(16) __bf16 sxs[72][64];   // 9.2KB
    __shared__ float sout[64][65];                 // 16.6KB
    const int tid = threadIdx.x;
    const int dir = blockIdx.z;
    const bf16* xs = xs2 + (size_t)dir * ((size_t)MROWS * EDIM);
    const float* w  = dir ? cw_b : cw_f;
    const float* cb = dir ? cb_b : cb_f;
    bf16* xct = xct2 + (size_t)dir * ((size_t)MROWS * EDIM);
    const int e0 = blockIdx.x * 64;
    const int bl0 = blockIdx.y * 64;
    const int lloc0 = bl0 & (LD - 1);
    const int b = bl0 >> 11;
    const int wave = tid >> 6, lane = tid & 63;

    for (int c = wave; c < 9; c += 4) {
        int g = bl0 - 8 + c * 8 + (lane >> 3);
        glds16(xs + (size_t)g * EDIM + e0 + (lane & 7) * 8, &sxs[c * 8][0]);
    }
    __syncthreads();
    if (lloc0 == 0 && tid < 192)
        sxs[5 + (tid >> 6)][tid & 63] = (__bf16)0.f;
    __syncthreads();

    {
        int lr4 = tid >> 6, e = tid & 63;
        float w0 = w[(e0 + e) * 4 + 0], w1 = w[(e0 + e) * 4 + 1];
        float w2 = w[(e0 + e) * 4 + 2], w3 = w[(e0 + e) * 4 + 3];
        float cbv = cb[e0 + e];
#pragma unroll
        for (int i = 0; i < 16; ++i) {
            int lr = i * 4 + lr4;
            float acc = cbv;
            acc = fmaf((float)sxs[lr + 5][e], w0, acc);
            acc = fmaf((float)sxs[lr + 6][e], w1, acc);
            acc = fmaf((float)sxs[lr + 7][e], w2, acc);
            acc = fmaf((float)sxs[lr + 8][e], w3, acc);
            sout[e][lr] = acc * sig_(acc);
        }
    }
    __syncthreads();
    {
        int l8 = (tid & 7) * 8;
#pragma unroll
        for (int i = 0; i < 2; ++i) {
            int er = i * 32 + (tid >> 3);
            bf16x8 o;
#pragma unroll
            for (int j = 0; j < 8; ++j) o[j] = (__bf16)sout[er][l8 + j];
            *(bf16x8*)(xct + ((size_t)b * EDIM + e0 + er) * LD + lloc0 + l8) = o;
        }
    }
}

// ---------------- g2m: MFMA dbl = xc @ xproj, BM=32 (1 block/CU) -------------
__global__ __launch_bounds__(256)
void g2m_k(const bf16* __restrict__ xct2, const bf16* __restrict__ xpT2,
           float* __restrict__ dblt2, float* __restrict__ dbldt2)
{
    __shared__ float As[32][33];            // [l][e] transposed, <=2-way banks
    __shared__ __align__(16) bf16 Bs[64][32];
    __shared__ float sDT[32][33];           // dt cols [l][n]
    __shared__ float sBC[32][33];           // BC cols [n-32][l]
    const int tid = threadIdx.x;
    const int dir = blockIdx.z;
    const bf16* xct = xct2 + (size_t)dir * ((size_t)MROWS * EDIM);
    const bf16* xpT = xpT2 + (size_t)dir * (64 * 1024);
    float* dblt = dblt2 + (size_t)dir * (2 * 64 * LD);
    float* dbldt = dbldt2 + (size_t)dir * (2 * 2048 * DTR);
    const int bm = blockIdx.y * 32;
    const int bB = bm >> 11, l0 = bm & (LD - 1);
    const int wave = tid >> 6, lane = tid & 63;
    const int wml = (wave >> 1) * 16, wnn = (wave & 1) * 32;
    const int lm = lane & 15, lq = lane >> 4;
    const int er = tid >> 3, l4 = (tid & 7) * 4;   // A-stage coords (32e x 32l)
    f32x4 acc[2] = {};

    for (int k0 = 0; k0 < EDIM; k0 += 32) {
        glds16(xpT + (size_t)(wave * 16 + (lane >> 2)) * 1024 + k0 + (lane & 3) * 8,
               &Bs[wave * 16][0]);
        {
            bf16x4 v = *(const bf16x4*)(xct +
                ((size_t)bB * EDIM + k0 + er) * LD + l0 + l4);
#pragma unroll
            for (int j = 0; j < 4; ++j) As[l4 + j][er] = (float)v[j];
        }
        __syncthreads();
        bf16x8 af;
#pragma unroll
        for (int j = 0; j < 8; ++j) af[j] = (__bf16)As[wml + lm][lq * 8 + j];
#pragma unroll
        for (int j = 0; j < 2; ++j) {
            bf16x8 bfr = *(const bf16x8*)&Bs[wnn + 16 * j + lm][lq * 8];
            acc[j] = __builtin_amdgcn_mfma_f32_16x16x32_bf16(af, bfr, acc[j], 0, 0, 0);
        }
        __syncthreads();
    }
    if (wnn == 0) {
#pragma unroll
        for (int j = 0; j < 2; ++j) {
            int col = 16 * j + lm;
#pragma unroll
            for (int r = 0; r < 4; ++r)
                sDT[wml + lq * 4 + r][col] = acc[j][r];
        }
    } else {
#pragma unroll
        for (int j = 0; j < 2; ++j) {
            int col = 16 * j + lm;
#pragma unroll
            for (int r = 0; r < 4; ++r)
                sBC[col][wml + lq * 4 + r] = acc[j][r];
        }
    }
    __syncthreads();
    {
        // dbldt [l][32] row-major, 16B per thread
        int row = tid >> 3, c4 = (tid & 7) * 4;
        float4 v = make_float4(sDT[row][c4], sDT[row][c4 + 1],
                               sDT[row][c4 + 2], sDT[row][c4 + 3]);
        *(float4*)(dbldt + (size_t)(bB * 2048 + l0 + row) * DTR + c4) = v;
    }
    {
        // dblt BC rows 32..63, 16B per thread
        int nr = tid >> 3, ll = (tid & 7) * 4;
        float4 v = make_float4(sBC[nr][ll], sBC[nr][ll + 1],
                               sBC[nr][ll + 2], sBC[nr][ll + 3]);
        *(float4*)(dblt + (size_t)(bB * 64 + 32 + nr) * LD + l0 + ll) = v;
    }
}

// ---------------- g3m: MFMA dlt_t = softplus(dbldt @ dtw + b)^T --------------
__global__ __launch_bounds__(256)
void g3m_k(const float* __restrict__ dbldt2, const bf16* __restrict__ dtwT2,
           const float* __restrict__ dtb_f, const float* __restrict__ dtb_b,
           bf16* __restrict__ dltt2)
{
    __shared__ __align__(16) bf16 As[64][40];
    __shared__ __align__(16) bf16 Bs[64][32];
    __shared__ float sC[64][65];
    const int tid = threadIdx.x;
    const int dir = blockIdx.z;
    const float* Ap = dbldt2 + (size_t)dir * (2 * 2048 * DTR);
    const bf16* BT = dtwT2 + (size_t)dir * (1024 * DTR);
    const float* bias = dir ? dtb_b : dtb_f;
    bf16* dltt = dltt2 + (size_t)dir * ((size_t)MROWS * EDIM);
    const int bm = blockIdx.y * 64, bn = blockIdx.x * 64;
    const int bB = bm >> 11, l0 = bm & (LD - 1);
    const int wave = tid >> 6, lane = tid & 63;
    const int wm = (wave >> 1) * 32, wn = (wave & 1) * 32;
    const int lm = lane & 15, lq = lane >> 4;

    {
        int row = tid >> 2, c8 = (tid & 3) * 8;
        const float* p = Ap + (size_t)(bB * 2048 + l0 + row) * DTR + c8;
        float4 v0 = *(const float4*)p, v1 = *(const float4*)(p + 4);
        bf16x8 o;
        o[0]=(__bf16)v0.x; o[1]=(__bf16)v0.y; o[2]=(__bf16)v0.z; o[3]=(__bf16)v0.w;
        o[4]=(__bf16)v1.x; o[5]=(__bf16)v1.y; o[6]=(__bf16)v1.z; o[7]=(__bf16)v1.w;
        *(bf16x8*)&As[row][c8] = o;
    }
    glds16(BT + (size_t)(bn + wave * 16 + (lane >> 2)) * DTR + (lane & 3) * 8,
           &Bs[wave * 16][0]);
    __syncthreads();

    bf16x8 af[2], bfr[2];
#pragma unroll
    for (int i = 0; i < 2; ++i)
        af[i] = *(const bf16x8*)&As[wm + 16 * i + lm][lq * 8];
#pragma unroll
    for (int j = 0; j < 2; ++j)
        bfr[j] = *(const bf16x8*)&Bs[wn + 16 * j + lm][lq * 8];
    f32x4 acc[2][2] = {};
#pragma unroll
    for (int i = 0; i < 2; ++i)
#pragma unroll
        for (int j = 0; j < 2; ++j)
            acc[i][j] = __builtin_amdgcn_mfma_f32_16x16x32_bf16(
                af[i], bfr[j], acc[i][j], 0, 0, 0);

#pragma unroll
    for (int i = 0; i < 2; ++i)
#pragma unroll
        for (int j = 0; j < 2; ++j) {
            int col = wn + 16 * j + lm;
            float bv = bias[bn + col];
#pragma unroll
            for (int r = 0; r < 4; ++r) {
                int row = wm + 16 * i + lq * 4 + r;
                float v = acc[i][j][r] + bv;
                v = (v > 20.f) ? v : log1pf(__expf(v));
                sC[col][row] = v;
            }
        }
    __syncthreads();
    {
        int erow = tid >> 2, l16 = (tid & 3) * 16;
        bf16* d = dltt + ((size_t)bB * EDIM + bn + erow) * LD + l0 + l16;
#pragma unroll
        for (int h = 0; h < 2; ++h) {
            bf16x8 o;
#pragma unroll
            for (int j = 0; j < 8; ++j) o[j] = (__bf16)sC[erow][l16 + h * 8 + j];
            *(bf16x8*)(d + h * 8) = o;
        }
    }
}

// ---------------- scan6 dir-merged: 256 chunks x 8 steps, parallel scan ------
__global__ __launch_bounds__(256)
void scan6_k(bf16* __restrict__ xct2, const bf16* __restrict__ dltt2,
             const float* __restrict__ dblt2,
             const float* __restrict__ alog_f, const float* __restrict__ alog_b,
             const float* __restrict__ dp_f, const float* __restrict__ dp_b)
{
    __shared__ float sA[NST];
    __shared__ float sWp[NST][4];
    __shared__ float sWs[NST][4];
    const int gid = blockIdx.x;                 // 0..4095
    const int dir = gid >> 11;
    const int bb  = (gid >> 10) & 1;
    const int e   = gid & (EDIM - 1);
    const float* A_log = dir ? alog_b : alog_f;
    const float* Dp    = dir ? dp_b   : dp_f;
    bf16* xct = xct2 + (size_t)dir * ((size_t)MROWS * EDIM);
    const bf16* dltt = dltt2 + (size_t)dir * ((size_t)MROWS * EDIM);
    const float* bt = dblt2 + (size_t)dir * (2 * 64 * LD) + (size_t)bb * 64 * LD;
    const int tid = threadIdx.x;
    const int wave = tid >> 6, lane = tid & 63;
    const size_t baset = ((size_t)bb * EDIM + e) * LD;
    const int l0 = tid * 8;

    if (tid < NST) sA[tid] = -__expf(A_log[e * NST + tid]);

    float xv[8], dv[8], dx[8];
    {
        bf16x8 xr = *(const bf16x8*)(xct + baset + l0);
        bf16x8 dr = *(const bf16x8*)(dltt + baset + l0);
#pragma unroll
        for (int j = 0; j < 8; ++j) { xv[j] = (float)xr[j]; dv[j] = (float)dr[j]; }
    }
#pragma unroll
    for (int j = 0; j < 8; ++j) dx[j] = dv[j] * xv[j];
    __syncthreads();

    float y[8] = {};
    for (int n = 0; n < NST; ++n) {
        const float An = sA[n];
        const float* Bp = bt + (size_t)(DTR + n) * LD + l0;
        const float* Cp = bt + (size_t)(DTR + NST + n) * LD + l0;
        float4 b0 = *(const float4*)Bp, b1 = *(const float4*)(Bp + 4);
        float4 c0 = *(const float4*)Cp, c1 = *(const float4*)(Cp + 4);
        float Br[8] = {b0.x,b0.y,b0.z,b0.w, b1.x,b1.y,b1.z,b1.w};
        float Cr[8] = {c0.x,c0.y,c0.z,c0.w, c1.x,c1.y,c1.z,c1.w};

        float S[8], P[8];
        float h = 0.f, pr = 1.f;
#pragma unroll
        for (int l = 0; l < 8; ++l) {
            float a = __expf(dv[l] * An);
            pr *= a;
            h = fmaf(a, h, dx[l] * Br[l]);
            P[l] = pr; S[l] = h;
        }

        float p = pr, s = h;
#pragma unroll
        for (int d = 1; d < 64; d <<= 1) {
            float pp = __shfl_up(p, d, 64);
            float sp = __shfl_up(s, d, 64);
            if (lane >= d) { s = fmaf(sp, p, s); p *= pp; }
        }
        if (lane == 63) { sWp[n][wave] = p; sWs[n][wave] = s; }
        __syncthreads();
        float Hoff = 0.f;
#pragma unroll
        for (int w = 0; w < 3; ++w)
            if (w < wave) Hoff = fmaf(sWp[n][w], Hoff, sWs[n][w]);
        float pprev = __shfl_up(p, 1, 64);
        float sprev = __shfl_up(s, 1, 64);
        float H = (lane == 0) ? Hoff : fmaf(pprev, Hoff, sprev);

#pragma unroll
        for (int l = 0; l < 8; ++l)
            y[l] = fmaf(Cr[l], fmaf(P[l], H, S[l]), y[l]);
    }

    const float Dv = Dp[e];
    bf16x8 o;
#pragma unroll
    for (int l = 0; l < 8; ++l) o[l] = (__bf16)fmaf(xv[l], Dv, y[l]);
    *(bf16x8*)(xct + baset + l0) = o;
}

// ---------------- layernorm (bf16 in-place), dir0 rows only ------------------
__global__ __launch_bounds__(256)
void ln_k(bf16* __restrict__ m, const float* __restrict__ gg,
          const float* __restrict__ bb)
{
    int row = (blockIdx.x * 256 + threadIdx.x) >> 6;
    int lane = threadIdx.x & 63;
    bf16* r = m + (size_t)row * DMODEL;
    float v[8], s = 0.f, s2 = 0.f;
#pragma unroll
    for (int i = 0; i < 8; ++i) {
        v[i] = __bfloat162float(r[lane + 64 * i]);
        s += v[i]; s2 = fmaf(v[i], v[i], s2);
    }
#pragma unroll
    for (int off = 32; off >= 1; off >>= 1) {
        s  += __shfl_xor(s, off, 64);
        s2 += __shfl_xor(s2, off, 64);
    }
    float mu = s * (1.f / DMODEL);
    float var = s2 * (1.f / DMODEL) - mu * mu;
    float inv = rsqrtf(var + 1e-5f);
#pragma unroll
    for (int i = 0; i < 8; ++i)
        r[lane + 64 * i] = __float2bfloat16(
            (v[i] - mu) * inv * gg[lane + 64 * i] + bb[lane + 64 * i]);
}

__global__ void sentinel_k(float* __restrict__ o)
{
    int i = blockIdx.x * 256 + threadIdx.x;
    o[i] = 100.0f;
}

extern "C" void kernel_launch(void* const* d_in, const int* in_sizes, int n_in,
                              void* d_out, int out_size, void* d_ws, size_t ws_size,
                              hipStream_t stream)
{
    const float* x    = (const float*)d_in[0];
    const float* n1g  = (const float*)d_in[19];
    const float* n1b  = (const float*)d_in[20];
    const float* fw1  = (const float*)d_in[23];
    const float* fb1  = (const float*)d_in[24];
    const float* fw2  = (const float*)d_in[25];
    const float* fb2  = (const float*)d_in[26];
    float* out = (float*)d_out;

    const size_t MiB = 1024 * 1024;
    const size_t SZ_DM = (size_t)MROWS * DMODEL;
    if (ws_size < 49 * MiB) {
        sentinel_k<<<dim3(SZ_DM / 256), dim3(256), 0, stream>>>(out);
        return;
    }

    // ---- 48.4 MiB layout ----
    char* base = (char*)d_ws;
    bf16* fw1T  = (bf16*)base;                 // [1024][512]        1 MiB
    bf16* fw2T  = (bf16*)(base + 1 * MiB);     // [512][1024]        1 MiB
    bf16* outwT = (bf16*)(base + 2 * MiB);     // [2][512][1024]     2 MiB
    bf16* inwT  = (bf16*)(base + 4 * MiB);     // [2][2048][512]     4 MiB
    bf16* xbf   = (bf16*)(base + 8 * MiB);     // [4096][512]        4 MiB
    char* RA    = base + 12 * MiB;             // 16 MiB: xs2 -> dltt2 -> yrow2 -> ffh2
    bf16* xs2   = (bf16*)RA;                   // [2][4096][1024]
    bf16* dltt2 = (bf16*)RA;
    bf16* yrow2 = (bf16*)RA;
    bf16* ffh2  = (bf16*)RA;
    char* RB    = base + 28 * MiB;             // 16 MiB: xct2 -> mbf2
    bf16* xct2  = (bf16*)RB;                   // [2][2][1024][2048]
    bf16* mbf2  = (bf16*)RB;                   // [2][4096][512]
    float* dblt2 = (float*)(base + 44 * MiB);  // [2][2][64][2048]   2 MiB (rows 32..63 used)
    float* dbldt2 = (float*)(base + 46 * MiB); // [2][2][2048][32]   2 MiB
    bf16* xpT2  = (bf16*)(base + 48 * MiB);               // [2][64][1024]  256 KiB
    bf16* dtwT2 = (bf16*)(base + 48 * MiB + 256 * 1024);  // [2][1024][32]  128 KiB

    const float* inw_f  = (const float*)d_in[1];
    const float* cw_f   = (const float*)d_in[2];
    const float* cb_f   = (const float*)d_in[3];
    const float* xp_f   = (const float*)d_in[4];
    const float* dtw_f  = (const float*)d_in[5];
    const float* dtb_f  = (const float*)d_in[6];
    const float* alog_f = (const float*)d_in[7];
    const float* dp_f   = (const float*)d_in[8];
    const float* outw_f = (const float*)d_in[9];
    const float* inw_b  = (const float*)d_in[10];
    const float* cw_b   = (const float*)d_in[11];
    const float* cb_b   = (const float*)d_in[12];
    const float* xp_b   = (const float*)d_in[13];
    const float* dtw_b  = (const float*)d_in[14];
    const float* dtb_b  = (const float*)d_in[15];
    const float* alog_b = (const float*)d_in[16];
    const float* dp_b   = (const float*)d_in[17];
    const float* outw_b = (const float*)d_in[18];

    dim3 blk(256);
    const size_t U = (size_t)MROWS * EDIM;   // 4,194,304 elems

    // 1. prep: all transposes + xconv
    prep_k<<<dim3(6336), blk, 0, stream>>>(x, xbf, inw_f, inw_b, inwT,
                                           outw_f, outw_b, outwT,
                                           fw1, fw1T, fw2, fw2T,
                                           xp_f, xp_b, xpT2,
                                           dtw_f, dtw_b, dtwT2);
    // 2. G1: xs2[dir] = x(flip d1) @ in_w[:, :1024]   M=4096 N=1024 K=512
    bgemm4_k<128, 128, 0, true, false><<<dim3(8, 32, 2), blk, 0, stream>>>(
        xbf, 0, DMODEL, inwT, (size_t)2048 * 512, DMODEL, nullptr,
        xs2, U, EDIM, nullptr, 0, nullptr, DMODEL);
    // 3. conv + silu + transpose (glds16-staged)
    conv3_k<<<dim3(16, 64, 2), blk, 0, stream>>>(xs2, cw_f, cb_f, cw_b, cb_b, xct2);
    // 4. G2 (MFMA): dblt rows 32..63 + dbldt row-major  (BM=32, 1 block/CU)
    g2m_k<<<dim3(1, 128, 2), blk, 0, stream>>>(xct2, xpT2, dblt2, dbldt2);
    // 5. G3 (MFMA): dltt2 (over dead xs2)
    g3m_k<<<dim3(16, 64, 2), blk, 0, stream>>>(dbldt2, dtwT2, dtb_f, dtb_b, dltt2);
    // 6. scan (in-place over xct2) — scan6 verbatim
    scan6_k<<<dim3(4096), blk, 0, stream>>>(xct2, dltt2, dblt2,
                                            alog_f, alog_b, dp_f, dp_b);
    // 7. zgate3: yrow2 = silu(x @ inw_z) * y  (writes over dead dltt2)
    zgate3_k<<<dim3(8, 64, 2), blk, 0, stream>>>(xbf, inwT, xct2, yrow2);
    // 8. G4: mbf2[dir] = y @ out_w   M=4096 N=512 K=1024
    bgemm4_k<128, 64, 0, false, false><<<dim3(8, 32, 2), blk, 0, stream>>>(
        yrow2, U, EDIM, outwT, (size_t)512 * 1024, EDIM, nullptr,
        mbf2, SZ_DM, DMODEL, nullptr, 0, nullptr, EDIM);
    // 9. LN on dir0 half of mbf2 (in place)
    ln_k<<<dim3(MROWS / 4), blk, 0, stream>>>(mbf2, n1g, n1b);
    // 10. G5: ffh2[dir] = relu(m @ fw1 + fb1)   M=4096 N=1024 K=512
    bgemm4_k<128, 128, 2, false, false><<<dim3(8, 32, 2), blk, 0, stream>>>(
        mbf2, SZ_DM, DMODEL, fw1T, 0, DMODEL, fb1,
        ffh2, U, DFF, nullptr, 0, nullptr, DMODEL);
    // 11. G6 fused (concat-K): out = ffh_f@fw2 + ffh_b@fw2 + 2*fb2 + m_f + m_b
    //     BM=64 -> (8,64,1) = 512 blocks = 2 blocks/CU, LDS 16KB
    bgemm4_k<64, 64, 5, false, true><<<dim3(8, 64, 1), blk, 0, stream>>>(
        ffh2, U, DFF, fw2T, 0, DFF, fb2,
        nullptr, 0, DMODEL, mbf2, SZ_DM, out, 2 * DFF);
}